// Round 1
// baseline (1121.968 us; speedup 1.0000x reference)
//
#include <hip/hip_runtime.h>
#include <math.h>

// Problem constants (B=8, H=W=128, C=128, R=4 -> 81 cost channels)
#define BATCH 8
#define HH 128
#define WW 128
#define CC 128
#define RR 4
#define DDIM 9
#define NS 81
#define HWPIX (HH*WW)

__device__ __forceinline__ float mish_f(float x){
    float sp = log1pf(expf(x));
    return x * tanhf(sp);
}

// ---------------------------------------------------------------------------
// Cost volume: cost[b,y,x,s] = mean_c prv[b,y,x,c]*nxt[b,y+dy,x+dx,c],
// s = (dy+4)*9 + (dx+4).  16x16 pixel tile per 256-thread block.
// nxt halo (24x24 px) staged in LDS, 8 channels/chunk, stride 12 floats
// (48B) per halo pixel so ds_read_b128 stays ~conflict-free.
// ---------------------------------------------------------------------------
__global__ __launch_bounds__(256,2) void cost_kernel(
    const float* __restrict__ prv, const float* __restrict__ nxt,
    float* __restrict__ cost)
{
    __shared__ float nx[24*24*12];
    const int tx = threadIdx.x & 15, ty = threadIdx.x >> 4;
    const int x0 = blockIdx.x*16, y0 = blockIdx.y*16, b = blockIdx.z;

    float acc[NS];
#pragma unroll
    for(int s=0;s<NS;s++) acc[s]=0.f;

    const float* prvp = prv + (((size_t)b*HH + (y0+ty))*WW + (x0+tx))*CC;

    for(int c0=0;c0<CC;c0+=8){
        __syncthreads();   // protect previous iteration's reads
        // stage nxt halo: 576 px * 8 ch as 2 float4 each
        for(int e=threadIdx.x; e<576*2; e+=256){
            int px = e>>1, hf = e&1;
            int hy = y0 - RR + px/24;
            int hx = x0 - RR + px%24;
            float4 v = {0.f,0.f,0.f,0.f};
            if(hy>=0 && hy<HH && hx>=0 && hx<WW)
                v = *(const float4*)(nxt + (((size_t)b*HH + hy)*WW + hx)*CC + c0 + hf*4);
            *(float4*)&nx[px*12 + hf*4] = v;
        }
        __syncthreads();
        float4 A  = *(const float4*)(prvp + c0);
        float4 Bv = *(const float4*)(prvp + c0 + 4);
#pragma unroll
        for(int i=0;i<DDIM;i++){
#pragma unroll
            for(int j=0;j<DDIM;j++){
                const float* q = &nx[((ty+i)*24 + (tx+j))*12];
                float4 n0 = *(const float4*)q;
                float4 n1 = *(const float4*)(q+4);
                float s = acc[i*DDIM+j];
                s = fmaf(A.x,n0.x,s);  s = fmaf(A.y,n0.y,s);
                s = fmaf(A.z,n0.z,s);  s = fmaf(A.w,n0.w,s);
                s = fmaf(Bv.x,n1.x,s); s = fmaf(Bv.y,n1.y,s);
                s = fmaf(Bv.z,n1.z,s); s = fmaf(Bv.w,n1.w,s);
                acc[i*DDIM+j] = s;
            }
        }
    }
    float* op = cost + (((size_t)b*HH + (y0+ty))*WW + (x0+tx))*NS;
#pragma unroll
    for(int s=0;s<NS;s++) op[s] = acc[s]*(1.f/128.f);
}

// ---------------------------------------------------------------------------
// Fused depthwise-3x3 + pointwise-1x1 (+bias +mish).
// 8x8 pixel tile / 256-thread block.  Channel chunks of 16:
//   phase 1: stage input halo (10x10 x ck) + pw chunk + dw chunk into LDS
//   phase 2: depthwise into LDS dsh[64][17]
//   phase 3: pointwise, register tile = 2 pixels x CPG couts / thread
// CONCAT=true: input channels are the virtual concat [cost|prv|nxt].
// All activation tensors are batch-relative; callers pre-offset pointers.
// ---------------------------------------------------------------------------
template<int CIN,int COUT,bool BIAS,bool ACT,bool CONCAT>
__global__ __launch_bounds__(256,4) void sep_kernel(
    const float* __restrict__ xin, const float* __restrict__ cost,
    const float* __restrict__ prv, const float* __restrict__ nxt,
    const float* __restrict__ dw,  const float* __restrict__ pw,
    const float* __restrict__ bias, float* __restrict__ out)
{
    constexpr int CPG = (COUT+7)/8;     // couts per thread-group (8 groups)
    __shared__ float xs [100*17];
    __shared__ float dsh[64*17];
    __shared__ float pwl[16*COUT];
    __shared__ float dwl[9*16];

    const int tid = threadIdx.x;
    const int x0 = blockIdx.x*8, y0 = blockIdx.y*8, b = blockIdx.z;
    const int p2  = tid & 31;           // pixel-pair index (pixels 2*p2, 2*p2+1)
    const int g   = tid >> 5;           // cout group 0..7
    const int co0 = g*CPG;

    float acc[2*CPG];
#pragma unroll
    for(int i=0;i<2*CPG;i++) acc[i]=0.f;

    for(int c0=0;c0<CIN;c0+=16){
        const int ck = (CIN-c0 >= 16) ? 16 : (CIN-c0);
        __syncthreads();   // protect previous iteration's pwl/xs reads
        // ---- stage input halo chunk ----
        for(int e=tid; e<100*ck; e+=256){
            int px, c;
            if(ck==16){ px=e>>4; c=e&15; } else { px=e/ck; c=e-px*ck; }
            int hy = y0-1 + px/10, hx = x0-1 + px%10;
            float v = 0.f;
            if(hy>=0 && hy<HH && hx>=0 && hx<WW){
                size_t pix = ((size_t)b*HH + hy)*WW + hx;
                int gc = c0 + c;
                if(CONCAT){
                    if(gc < 81)       v = cost[pix*81  + gc];
                    else if(gc < 209) v = prv [pix*128 + (gc-81)];
                    else              v = nxt [pix*128 + (gc-209)];
                } else {
                    v = xin[pix*CIN + gc];
                }
            }
            xs[px*17+c] = v;
        }
        // ---- stage pointwise weight chunk (linear copy, coalesced) ----
        for(int e=tid; e<ck*COUT; e+=256) pwl[e] = pw[(size_t)c0*COUT + e];
        // ---- stage depthwise weight chunk ----
        for(int e=tid; e<9*ck; e+=256){
            int k, c;
            if(ck==16){ k=e>>4; c=e&15; } else { k=e/ck; c=e-k*ck; }
            dwl[k*16+c] = dw[k*CIN + c0 + c];
        }
        __syncthreads();
        // ---- depthwise 3x3 ----
        for(int idx=tid; idx<64*ck; idx+=256){
            int px = idx & 63, c = idx >> 6;
            int py = px>>3, pxx = px&7;
            float s = 0.f;
#pragma unroll
            for(int kh=0;kh<3;kh++)
#pragma unroll
                for(int kw=0;kw<3;kw++)
                    s = fmaf(xs[((py+kh)*10 + (pxx+kw))*17 + c],
                             dwl[(kh*3+kw)*16 + c], s);
            dsh[px*17+c] = s;
        }
        __syncthreads();
        // ---- pointwise accumulate ----
        if(co0 < COUT){
            for(int cin=0; cin<ck; cin++){
                float a0 = dsh[(2*p2  )*17 + cin];
                float a1 = dsh[(2*p2+1)*17 + cin];
                const float* pr = &pwl[cin*COUT + co0];
                if constexpr ((CPG & 3) == 0){
#pragma unroll
                    for(int q=0;q<CPG/4;q++){
                        float4 w = *(const float4*)(pr + 4*q);
                        acc[4*q+0]     = fmaf(a0,w.x,acc[4*q+0]);
                        acc[4*q+1]     = fmaf(a0,w.y,acc[4*q+1]);
                        acc[4*q+2]     = fmaf(a0,w.z,acc[4*q+2]);
                        acc[4*q+3]     = fmaf(a0,w.w,acc[4*q+3]);
                        acc[CPG+4*q+0] = fmaf(a1,w.x,acc[CPG+4*q+0]);
                        acc[CPG+4*q+1] = fmaf(a1,w.y,acc[CPG+4*q+1]);
                        acc[CPG+4*q+2] = fmaf(a1,w.z,acc[CPG+4*q+2]);
                        acc[CPG+4*q+3] = fmaf(a1,w.w,acc[CPG+4*q+3]);
                    }
                } else {
#pragma unroll
                    for(int j=0;j<CPG;j++){
                        float w = pr[j];
                        acc[j]     = fmaf(a0,w,acc[j]);
                        acc[CPG+j] = fmaf(a1,w,acc[CPG+j]);
                    }
                }
            }
        }
    }
    // ---- epilogue ----
    if(co0 < COUT){
#pragma unroll
        for(int h=0;h<2;h++){
            int px = 2*p2 + h;
            int y = y0 + (px>>3), x = x0 + (px&7);
            float* op = out + (((size_t)b*HH + y)*WW + x)*COUT + co0;
#pragma unroll
            for(int j=0;j<CPG;j++){
                float v = acc[h*CPG+j];
                if(BIAS) v += bias[co0+j];
                if(ACT)  v = mish_f(v);
                op[j] = v;
            }
        }
    }
}

// ---------------------------------------------------------------------------
extern "C" void kernel_launch(void* const* d_in, const int* in_sizes, int n_in,
                              void* d_out, int out_size, void* d_ws, size_t ws_size,
                              hipStream_t stream)
{
    (void)in_sizes; (void)n_in; (void)out_size;
    const float* prv = (const float*)d_in[0];
    const float* nxt = (const float*)d_in[1];
    const float* dw0 = (const float*)d_in[2];
    const float* pw0 = (const float*)d_in[3];
    const float* b0  = (const float*)d_in[4];
    const float* dw1 = (const float*)d_in[5];
    const float* pw1 = (const float*)d_in[6];
    const float* b1  = (const float*)d_in[7];
    const float* dw2 = (const float*)d_in[8];
    const float* pw2 = (const float*)d_in[9];
    const float* b2  = (const float*)d_in[10];
    const float* dw3 = (const float*)d_in[11];
    const float* pw3 = (const float*)d_in[12];
    const float* b3  = (const float*)d_in[13];
    const float* dw4 = (const float*)d_in[14];
    const float* pw4 = (const float*)d_in[15];
    const float* b4  = (const float*)d_in[16];
    const float* dw5 = (const float*)d_in[17];
    const float* pw5 = (const float*)d_in[18];

    // Workspace per batch: cost 81 + bufA 128 + bufB 128 = 337 ch * 16384 px
    // = 22.1 MB.  Chunk over batch if ws_size is small (NB divides 8).
    const size_t per_batch_floats = (size_t)HWPIX * (NS + 128 + 128);
    int NB = (int)(ws_size / (per_batch_floats * sizeof(float)));
    if(NB > BATCH) NB = BATCH;
    if(NB < 1)     NB = 1;              // assume ws >= 23 MB
    while(BATCH % NB) NB--;             // NB in {8,4,2,1}

    float* ws    = (float*)d_ws;
    float* costb = ws;
    float* bufA  = costb + (size_t)NB*HWPIX*NS;
    float* bufB  = bufA  + (size_t)NB*HWPIX*128;

    for(int bb=0; bb<BATCH; bb+=NB){
        const float* prv_o = prv + (size_t)bb*HWPIX*CC;
        const float* nxt_o = nxt + (size_t)bb*HWPIX*CC;
        float*       out_o = (float*)d_out + (size_t)bb*HWPIX*2;
        dim3 gc(WW/16, HH/16, NB);
        dim3 gs(WW/8,  HH/8,  NB);

        cost_kernel<<<gc,256,0,stream>>>(prv_o, nxt_o, costb);
        sep_kernel<337,128,true ,true ,true ><<<gs,256,0,stream>>>(nullptr, costb, prv_o, nxt_o, dw0, pw0, b0, bufA);
        sep_kernel<128,128,true ,true ,false><<<gs,256,0,stream>>>(bufA, nullptr,nullptr,nullptr, dw1, pw1, b1, bufB);
        sep_kernel<128, 96,true ,true ,false><<<gs,256,0,stream>>>(bufB, nullptr,nullptr,nullptr, dw2, pw2, b2, bufA);
        sep_kernel< 96, 64,true ,true ,false><<<gs,256,0,stream>>>(bufA, nullptr,nullptr,nullptr, dw3, pw3, b3, bufB);
        sep_kernel< 64, 32,true ,true ,false><<<gs,256,0,stream>>>(bufB, nullptr,nullptr,nullptr, dw4, pw4, b4, bufA);
        sep_kernel< 32,  2,false,false,false><<<gs,256,0,stream>>>(bufA, nullptr,nullptr,nullptr, dw5, pw5, nullptr, out_o);
    }
}

// Round 3
// 748.819 us; speedup vs baseline: 1.4983x; 1.4983x over previous
//
#include <hip/hip_runtime.h>
#include <math.h>

// Problem constants (B=8, H=W=128, C=128, R=4 -> 81 cost channels)
#define BATCH 8
#define HH 128
#define WW 128
#define CC 128
#define RR 4
#define DDIM 9
#define NS 81
#define HWPIX (HH*WW)

typedef short  short8 __attribute__((ext_vector_type(8)));
typedef short  short4v __attribute__((ext_vector_type(4)));
typedef float  f32x4  __attribute__((ext_vector_type(4)));

__device__ __forceinline__ short bf16h(float f){
    // fp32 -> bf16 bits, round-to-nearest-even
    unsigned u = __float_as_uint(f);
    u += 0x7fffu + ((u >> 16) & 1u);
    return (short)(u >> 16);
}
__device__ __forceinline__ float bf16f(short s){
    return __uint_as_float(((unsigned)(unsigned short)s) << 16);
}

__device__ __forceinline__ float mish_f(float x){
    // mish(x) = x * tanh(softplus(x)) = x * (t^2+2t)/(t^2+2t+2), t = e^x
    float xc = fminf(x, 30.f);
    float t = expf(xc);
    float u = t*t + 2.f*t;
    return x * (u / (u + 2.f));
}

// ---------------------------------------------------------------------------
// Cost volume (unchanged): 16x16 px tile, nxt halo in LDS.
// ---------------------------------------------------------------------------
__global__ __launch_bounds__(256,2) void cost_kernel(
    const float* __restrict__ prv, const float* __restrict__ nxt,
    float* __restrict__ cost)
{
    __shared__ float nx[24*24*12];
    const int tx = threadIdx.x & 15, ty = threadIdx.x >> 4;
    const int x0 = blockIdx.x*16, y0 = blockIdx.y*16, b = blockIdx.z;

    float acc[NS];
#pragma unroll
    for(int s=0;s<NS;s++) acc[s]=0.f;

    const float* prvp = prv + (((size_t)b*HH + (y0+ty))*WW + (x0+tx))*CC;

    for(int c0=0;c0<CC;c0+=8){
        __syncthreads();
        for(int e=threadIdx.x; e<576*2; e+=256){
            int px = e>>1, hf = e&1;
            int hy = y0 - RR + px/24;
            int hx = x0 - RR + px%24;
            float4 v = {0.f,0.f,0.f,0.f};
            if(hy>=0 && hy<HH && hx>=0 && hx<WW)
                v = *(const float4*)(nxt + (((size_t)b*HH + hy)*WW + hx)*CC + c0 + hf*4);
            *(float4*)&nx[px*12 + hf*4] = v;
        }
        __syncthreads();
        float4 A  = *(const float4*)(prvp + c0);
        float4 Bv = *(const float4*)(prvp + c0 + 4);
#pragma unroll
        for(int i=0;i<DDIM;i++){
#pragma unroll
            for(int j=0;j<DDIM;j++){
                const float* q = &nx[((ty+i)*24 + (tx+j))*12];
                float4 n0 = *(const float4*)q;
                float4 n1 = *(const float4*)(q+4);
                float s = acc[i*DDIM+j];
                s = fmaf(A.x,n0.x,s);  s = fmaf(A.y,n0.y,s);
                s = fmaf(A.z,n0.z,s);  s = fmaf(A.w,n0.w,s);
                s = fmaf(Bv.x,n1.x,s); s = fmaf(Bv.y,n1.y,s);
                s = fmaf(Bv.z,n1.z,s); s = fmaf(Bv.w,n1.w,s);
                acc[i*DDIM+j] = s;
            }
        }
    }
    float* op = cost + (((size_t)b*HH + (y0+ty))*WW + (x0+tx))*NS;
#pragma unroll
    for(int s=0;s<NS;s++) op[s] = acc[s]*(1.f/128.f);
}

// ---------------------------------------------------------------------------
// Pointwise weight prep: split fp32 pw weights into hi/lo bf16 slabs laid out
// as B-fragments: dst[(k8*NP + n)*8 + j]  (k = k8*8+j), zero-padded to K0/NP.
// ---------------------------------------------------------------------------
__global__ void prep_pw(const float* __restrict__ src, short* __restrict__ dh,
                        short* __restrict__ dl, int K, int N, int NP, int total)
{
    int idx = blockIdx.x*256 + threadIdx.x;
    if(idx >= total) return;
    int j  = idx & 7;
    int n  = (idx>>3) % NP;
    int k8 = (idx>>3) / NP;
    int k  = k8*8 + j;
    float v = (k<K && n<N) ? src[(size_t)k*N + n] : 0.f;
    short h = bf16h(v);
    dh[idx] = h;
    dl[idx] = bf16h(v - bf16f(h));
}

// ---------------------------------------------------------------------------
// Fused depthwise-3x3 (fp32 VALU) + pointwise-1x1 (split-bf16 MFMA, fp32 acc).
// Tile: 16(w) x 8(h) = 128 px, 4 waves in a 2(m) x 2(n) grid.
// bf16 (not f16): activations/weight-lo parts reach ~1e-5..2e-5 at late
// layers, inside f16's subnormal range (min normal 6.1e-5) -> f16 MFMA
// flushed them (round-2 failure, absmax 43% of ref). bf16 exponent = fp32.
// ---------------------------------------------------------------------------
template<int CINR,int K0,int COUT,int NP,bool BIAS,bool ACT,bool CONCAT>
__global__ __launch_bounds__(256,3) void sep_mfma(
    const float* __restrict__ xin, const float* __restrict__ cost,
    const float* __restrict__ prv, const float* __restrict__ nxt,
    const float* __restrict__ dwv, const short* __restrict__ wh,
    const short* __restrict__ wl, const float* __restrict__ bias,
    float* __restrict__ out)
{
    constexpr int TN = NP/32;           // n-tiles per wave (16 couts each)
    __shared__ float xs[180*36];        // halo 10(y) x 18(x), 32 ch, stride 36
    __shared__ short dshh[4*128*8];     // [k8][px][j]  hi
    __shared__ short dshl[4*128*8];     // [k8][px][j]  lo
    __shared__ float dwls[9*32];

    const int tid = threadIdx.x;
    const int x0 = blockIdx.x*16, y0 = blockIdx.y*8, b = blockIdx.z;
    const int lane = tid & 63;
    const int wv   = tid >> 6;
    const int wm   = wv >> 1, wn = wv & 1;
    const int l15  = lane & 15, quad = lane >> 4;

    f32x4 acc[4][TN];
#pragma unroll
    for(int i=0;i<4;i++)
#pragma unroll
        for(int nt=0;nt<TN;nt++) acc[i][nt] = (f32x4){0.f,0.f,0.f,0.f};

    for(int c0=0;c0<K0;c0+=32){
        __syncthreads();
        // ---- stage input halo chunk ----
        if(CONCAT){
            for(int e=tid; e<180*32; e+=256){
                int hp = e>>5, c = e&31;
                int hy = y0-1 + hp/18, hx = x0-1 + hp%18;
                float v = 0.f;
                int gc = c0 + c;
                if(hy>=0 && hy<HH && hx>=0 && hx<WW && gc<CINR){
                    size_t pix = ((size_t)b*HH + hy)*WW + hx;
                    if(gc < 81)       v = cost[pix*81  + gc];
                    else if(gc < 209) v = prv [pix*128 + (gc-81)];
                    else              v = nxt [pix*128 + (gc-209)];
                }
                xs[hp*36 + c] = v;
            }
        } else {
            for(int e=tid; e<180*8; e+=256){
                int hp = e>>3, c4 = e&7;
                int hy = y0-1 + hp/18, hx = x0-1 + hp%18;
                float4 v = {0.f,0.f,0.f,0.f};
                if(hy>=0 && hy<HH && hx>=0 && hx<WW){
                    size_t pix = ((size_t)b*HH + hy)*WW + hx;
                    v = *(const float4*)(xin + pix*CINR + c0 + c4*4);
                }
                *(float4*)&xs[hp*36 + c4*4] = v;
            }
        }
        // ---- stage depthwise weights ----
        for(int e=tid; e<288; e+=256){
            int k = e>>5, c = e&31;
            dwls[e] = (c0+c < CINR) ? dwv[k*CINR + c0 + c] : 0.f;
        }
        __syncthreads();
        // ---- depthwise 3x3 + split to bf16 hi/lo ----
#pragma unroll
        for(int r=0;r<4;r++){
            int idx = r*256 + tid;
            int c4 = idx&7, px = idx>>3;
            int py = px>>4, pxx = px&15;
            float4 s = {0.f,0.f,0.f,0.f};
#pragma unroll
            for(int kh=0;kh<3;kh++)
#pragma unroll
                for(int kw=0;kw<3;kw++){
                    float4 xv = *(const float4*)&xs[((py+kh)*18 + (pxx+kw))*36 + c4*4];
                    float4 wv4= *(const float4*)&dwls[(kh*3+kw)*32 + c4*4];
                    s.x = fmaf(xv.x,wv4.x,s.x); s.y = fmaf(xv.y,wv4.y,s.y);
                    s.z = fmaf(xv.z,wv4.z,s.z); s.w = fmaf(xv.w,wv4.w,s.w);
                }
            short4v h, l;
            h.x=bf16h(s.x); l.x=bf16h(s.x-bf16f(h.x));
            h.y=bf16h(s.y); l.y=bf16h(s.y-bf16f(h.y));
            h.z=bf16h(s.z); l.z=bf16h(s.z-bf16f(h.z));
            h.w=bf16h(s.w); l.w=bf16h(s.w-bf16f(h.w));
            int base = (c4>>1)*1024 + px*8 + (c4&1)*4;
            *(short4v*)&dshh[base] = h;
            *(short4v*)&dshl[base] = l;
        }
        __syncthreads();
        // ---- MFMA: A from LDS, B straight from L2 ----
        short8 Ah[4], Al[4];
#pragma unroll
        for(int i=0;i<4;i++){
            int ab = quad*1024 + (wm*64 + i*16 + l15)*8;
            Ah[i] = *(const short8*)&dshh[ab];
            Al[i] = *(const short8*)&dshl[ab];
        }
        const int k8 = (c0>>3) + quad;
        short8 Bh[TN], Bl[TN];
#pragma unroll
        for(int nt=0;nt<TN;nt++){
            int n = wn*(NP/2) + nt*16 + l15;
            size_t off = ((size_t)k8*NP + n)*8;
            Bh[nt] = *(const short8*)(wh + off);
            Bl[nt] = *(const short8*)(wl + off);
        }
#pragma unroll
        for(int i=0;i<4;i++)
#pragma unroll
            for(int nt=0;nt<TN;nt++){
                f32x4 c = acc[i][nt];
                c = __builtin_amdgcn_mfma_f32_16x16x32_bf16(Ah[i],Bh[nt],c,0,0,0);
                c = __builtin_amdgcn_mfma_f32_16x16x32_bf16(Al[i],Bh[nt],c,0,0,0);
                c = __builtin_amdgcn_mfma_f32_16x16x32_bf16(Ah[i],Bl[nt],c,0,0,0);
                acc[i][nt] = c;
            }
    }
    // ---- epilogue: bias + mish + store ----
#pragma unroll
    for(int i=0;i<4;i++){
        int pxb = wm*64 + i*16 + quad*4;
#pragma unroll
        for(int nt=0;nt<TN;nt++){
            int cout = wn*(NP/2) + nt*16 + l15;
            if(cout < COUT){
                float bv = BIAS ? bias[cout] : 0.f;
#pragma unroll
                for(int r=0;r<4;r++){
                    int p = pxb + r;
                    int y = y0 + (p>>4), x = x0 + (p&15);
                    float v = acc[i][nt][r] + bv;
                    if(ACT) v = mish_f(v);
                    out[(((size_t)b*HH + y)*WW + x)*COUT + cout] = v;
                }
            }
        }
    }
}

// ---------------------------------------------------------------------------
extern "C" void kernel_launch(void* const* d_in, const int* in_sizes, int n_in,
                              void* d_out, int out_size, void* d_ws, size_t ws_size,
                              hipStream_t stream)
{
    (void)in_sizes; (void)n_in; (void)out_size;
    const float* prv = (const float*)d_in[0];
    const float* nxt = (const float*)d_in[1];
    const float* dw0 = (const float*)d_in[2];
    const float* pw0 = (const float*)d_in[3];
    const float* b0  = (const float*)d_in[4];
    const float* dw1 = (const float*)d_in[5];
    const float* pw1 = (const float*)d_in[6];
    const float* b1  = (const float*)d_in[7];
    const float* dw2 = (const float*)d_in[8];
    const float* pw2 = (const float*)d_in[9];
    const float* b2  = (const float*)d_in[10];
    const float* dw3 = (const float*)d_in[11];
    const float* pw3 = (const float*)d_in[12];
    const float* b3  = (const float*)d_in[13];
    const float* dw4 = (const float*)d_in[14];
    const float* pw4 = (const float*)d_in[15];
    const float* b4  = (const float*)d_in[16];
    const float* dw5 = (const float*)d_in[17];
    const float* pw5 = (const float*)d_in[18];

    // ---- weight slabs (hi/lo bf16, B-fragment layout) at start of ws ----
    const int   Ks[6]  = {337,128,128, 96, 64, 32};
    const int   K0s[6] = {352,128,128, 96, 64, 32};
    const int   Ns[6]  = {128,128, 96, 64, 32,  2};
    const int   NPs[6] = {128,128, 96, 64, 32, 32};
    const float* pws[6] = {pw0,pw1,pw2,pw3,pw4,pw5};
    size_t offs[6]; size_t E = 0;
    for(int i=0;i<6;i++){ offs[i] = E; E += (size_t)K0s[i]*NPs[i]; }
    short* Whs = (short*)d_ws;
    short* Wls = Whs + E;
    size_t wbytes = ((E*2*sizeof(short)) + 255) & ~(size_t)255;

    for(int i=0;i<6;i++){
        int total = K0s[i]*NPs[i];
        prep_pw<<<(total+255)/256,256,0,stream>>>(pws[i], Whs+offs[i], Wls+offs[i],
                                                  Ks[i], Ns[i], NPs[i], total);
    }

    // ---- activation buffers, batch-chunked ----
    const size_t per_batch_floats = (size_t)HWPIX * (NS + 128 + 128);
    size_t avail = (ws_size > wbytes) ? (ws_size - wbytes) : 0;
    int NB = (int)(avail / (per_batch_floats * sizeof(float)));
    if(NB > BATCH) NB = BATCH;
    if(NB < 1)     NB = 1;
    while(BATCH % NB) NB--;

    float* fbase = (float*)((char*)d_ws + wbytes);
    float* costb = fbase;
    float* bufA  = costb + (size_t)NB*HWPIX*NS;
    float* bufB  = bufA  + (size_t)NB*HWPIX*128;

    for(int bb=0; bb<BATCH; bb+=NB){
        const float* prv_o = prv + (size_t)bb*HWPIX*CC;
        const float* nxt_o = nxt + (size_t)bb*HWPIX*CC;
        float*       out_o = (float*)d_out + (size_t)bb*HWPIX*2;
        dim3 gc(WW/16, HH/16, NB);
        dim3 gs(WW/16, HH/8,  NB);

        cost_kernel<<<gc,256,0,stream>>>(prv_o, nxt_o, costb);
        sep_mfma<337,352,128,128,true ,true ,true ><<<gs,256,0,stream>>>(nullptr, costb, prv_o, nxt_o, dw0, Whs+offs[0], Wls+offs[0], b0, bufA);
        sep_mfma<128,128,128,128,true ,true ,false><<<gs,256,0,stream>>>(bufA, nullptr,nullptr,nullptr, dw1, Whs+offs[1], Wls+offs[1], b1, bufB);
        sep_mfma<128,128, 96, 96,true ,true ,false><<<gs,256,0,stream>>>(bufB, nullptr,nullptr,nullptr, dw2, Whs+offs[2], Wls+offs[2], b2, bufA);
        sep_mfma< 96, 96, 64, 64,true ,true ,false><<<gs,256,0,stream>>>(bufA, nullptr,nullptr,nullptr, dw3, Whs+offs[3], Wls+offs[3], b3, bufB);
        sep_mfma< 64, 64, 32, 32,true ,true ,false><<<gs,256,0,stream>>>(bufB, nullptr,nullptr,nullptr, dw4, Whs+offs[4], Wls+offs[4], b4, bufA);
        sep_mfma< 32, 32,  2, 32,false,false,false><<<gs,256,0,stream>>>(bufA, nullptr,nullptr,nullptr, dw5, Whs+offs[5], Wls+offs[5], nullptr, out_o);
    }
}